// Round 4
// baseline (6206.729 us; speedup 1.0000x reference)
//
#include <hip/hip_runtime.h>

typedef unsigned short u16;
typedef __bf16 bf16x8 __attribute__((ext_vector_type(8)));
typedef float f32x4 __attribute__((ext_vector_type(4)));

static __device__ __forceinline__ float bf2f(u16 v){ unsigned u=((unsigned)v)<<16; float f; __builtin_memcpy(&f,&u,4); return f; }
static __device__ __forceinline__ u16 f2bf(float f){ unsigned u; __builtin_memcpy(&u,&f,4); u += 0x7fffu + ((u>>16)&1u); return (u16)(u>>16); }

static __device__ __forceinline__ float wave_max(float v){
#pragma unroll
  for(int o=32;o;o>>=1) v=fmaxf(v,__shfl_xor(v,o,64));
  return v;
}
static __device__ __forceinline__ float wave_sum(float v){
#pragma unroll
  for(int o=32;o;o>>=1) v+=__shfl_xor(v,o,64);
  return v;
}

__global__ void k_sentinel(u16* __restrict__ o, float v){ o[0] = f2bf(v); }

// dtype probe: if any u16 half of x's first 32768 words has exponent field 0xFF,
// the data cannot be finite bf16 -> it is f32 mantissa bits. flag=1 => f32 inputs.
__global__ void k_probe(const unsigned* __restrict__ w, int* __restrict__ flag){
  __shared__ int found;
  if (threadIdx.x==0) found = 0;
  __syncthreads();
  int loc = 0;
  for (int i = threadIdx.x; i < 32768; i += 256){
    unsigned v = w[i];
    if ((((v >> 7) & 0xFFu) == 0xFFu) || (((v >> 23) & 0xFFu) == 0xFFu)) loc = 1;
  }
  if (loc) atomicOr(&found, 1);
  __syncthreads();
  if (threadIdx.x==0) *flag = found;
}

// normalize a tensor to bf16 (identity copy if already bf16)
__global__ void k_cvt(const void* __restrict__ src, u16* __restrict__ dst, int n, const int* __restrict__ flag){
  int i = blockIdx.x*256 + threadIdx.x;
  if (i >= n) return;
  if (*flag) dst[i] = f2bf(((const float*)src)[i]);
  else       dst[i] = ((const u16*)src)[i];
}

__global__ void k_zero(uint4* __restrict__ p, long n){
  long i = (long)blockIdx.x*256 + threadIdx.x;
  if (i < n) p[i] = make_uint4(0,0,0,0);
}

// NCHW x, channel window [icoff, icoff+ICD) of the flattened (b*2048+ic) axis
// -> zero-padded NHWC [66][66][ICD]
__global__ void k_pad1(const void* __restrict__ xb, u16* __restrict__ xp, int ICD, int icoff,
                       const int* __restrict__ flag){
  __shared__ u16 tile[64][65];
  const int h = blockIdx.x;
  const int ic0 = blockIdx.y<<6;
  const int t = threadIdx.x, lane = t&63, g = t>>6;
  const size_t base = (size_t)(icoff+ic0)*4096 + (size_t)h*64;
  if (*flag){
    const float* src = (const float*)xb + base;
#pragma unroll
    for(int i=0;i<16;i++){ int icl = g*16+i; tile[icl][lane] = f2bf(src[(size_t)icl*4096 + lane]); }
  } else {
    const u16* src = (const u16*)xb + base;
#pragma unroll
    for(int i=0;i<16;i++){ int icl = g*16+i; tile[icl][lane] = src[(size_t)icl*4096 + lane]; }
  }
  __syncthreads();
  u16* dst = xp + (((size_t)(h+1))*66 + 1)*ICD + ic0;
#pragma unroll
  for(int j=0;j<16;j++){ int w = g*16+j; dst[(size_t)w*ICD + lane] = tile[lane][w]; }
}

// OIHW 3x3 weights (OC=512, src IC count ICS), ic window [icoff,icoff+ICD) -> [tap][oc][icd]
__global__ void k_wtrans(const void* __restrict__ w, u16* __restrict__ wt, int ICS, int ICD, int icoff,
                         const int* __restrict__ flag){
  size_t i = (size_t)blockIdx.x*256 + threadIdx.x;  // grid sized exactly 9*512*ICD/256
  int icd = (int)(i & (ICD-1));
  size_t rest = i / ICD;
  int oc = (int)(rest & 511);
  int tap = (int)(rest >> 9);
  size_t sidx = ((size_t)oc*ICS + icoff + icd)*9 + tap;
  wt[i] = (*flag) ? f2bf(((const float*)w)[sidx]) : ((const u16*)w)[sidx];
}

// bf16 transpose [R][C] -> [C][R]
__global__ void k_transpose(const u16* __restrict__ in, u16* __restrict__ outp, int R, int C){
  __shared__ u16 tile[64][65];
  const int c0 = blockIdx.x<<6, r0 = blockIdx.y<<6;
  const int t=threadIdx.x, lane=t&63, g=t>>6;
#pragma unroll
  for(int i=0;i<16;i++){ int rl=g*16+i; tile[rl][lane] = in[(size_t)(r0+rl)*C + c0 + lane]; }
  __syncthreads();
#pragma unroll
  for(int j=0;j<16;j++){ int cl=g*16+j; outp[(size_t)(c0+cl)*R + r0 + lane] = tile[lane][cl]; }
}

// NHWC strip [npix][C] (npix=8192 => 2 batches) -> padded [2][66][66][C] interior
__global__ void k_pad_strip(const u16* __restrict__ in, u16* __restrict__ outp, int C, int npix){
  long i = (long)blockIdx.x*256 + threadIdx.x;   // vec8 index
  int vpp = C>>3;
  if (i >= (long)npix*vpp) return;
  int p = (int)(i/vpp), v = (int)(i - (long)p*vpp);
  int b = p>>12, h=(p>>6)&63, w=p&63;
  ((uint4*)outp)[((size_t)(b*66+h+1)*66 + (w+1))*vpp + v] = ((const uint4*)in)[i];
}

__global__ void k_add_bf16(const u16* __restrict__ a, const u16* __restrict__ b, u16* __restrict__ o, long n){
  long i = ((long)blockIdx.x*256 + threadIdx.x)*8;
  if (i >= n) return;
  uint4 va = *(const uint4*)(a+i), vb = *(const uint4*)(b+i);
  u16* pa=(u16*)&va; u16* pb=(u16*)&vb;
  uint4 vo; u16* po=(u16*)&vo;
#pragma unroll
  for(int e=0;e<8;e++) po[e] = f2bf(bf2f(pa[e]) + bf2f(pb[e]));
  *(uint4*)(o+i) = vo;
}

// generic NT GEMM: C[MxN] = A[MxK] * Bt[NxK]^T
// mode 0: bf16 plain; 1: bf16 + bias q1[col]; 3: bf16 alpha(q1[0])*acc + resid q2[idx]; 4: f32 plain.
__global__ __launch_bounds__(256,2) void gemm_nt(
    const u16* __restrict__ A, const u16* __restrict__ Bt,
    int N, int K, int lda, int ldb,
    void* __restrict__ Cout, int ldc, int mode,
    const u16* __restrict__ q1, const u16* __restrict__ q2)
{
  __shared__ __align__(16) u16 As[128*40];
  __shared__ __align__(16) u16 Bs[128*40];
  const int t = threadIdx.x;
  const int m0 = blockIdx.y<<7, n0 = blockIdx.x<<7;
  const int r = t>>2, q = t&3;
  const u16* A0 = A + (size_t)(m0+r)*lda + q*8;
  const u16* A1 = A0 + (size_t)64*lda;
  const bool bv0 = (n0+r)    < N;
  const bool bv1 = (n0+r+64) < N;
  const u16* B0 = Bt + (size_t)(n0+r)*ldb + q*8;
  const u16* B1 = B0 + (size_t)64*ldb;
  const int wave=t>>6, lane=t&63;
  const int wr=(wave>>1)<<6, wc=(wave&1)<<6, fm=lane&15, kg=lane>>4;
  f32x4 acc[4][4] = {};
  for (int k0=0; k0<K; k0+=32){
    uint4 a0 = *(const uint4*)(A0+k0);
    uint4 a1 = *(const uint4*)(A1+k0);
    uint4 b0 = bv0 ? *(const uint4*)(B0+k0) : make_uint4(0,0,0,0);
    uint4 b1 = bv1 ? *(const uint4*)(B1+k0) : make_uint4(0,0,0,0);
    __syncthreads();
    *(uint4*)&As[r*40+q*8] = a0;
    *(uint4*)&As[(r+64)*40+q*8] = a1;
    *(uint4*)&Bs[r*40+q*8] = b0;
    *(uint4*)&Bs[(r+64)*40+q*8] = b1;
    __syncthreads();
    bf16x8 af[4], bfr[4];
#pragma unroll
    for(int i=0;i<4;i++) af[i]  = *(const bf16x8*)&As[(wr+i*16+fm)*40 + kg*8];
#pragma unroll
    for(int j=0;j<4;j++) bfr[j] = *(const bf16x8*)&Bs[(wc+j*16+fm)*40 + kg*8];
#pragma unroll
    for(int i=0;i<4;i++)
#pragma unroll
      for(int j=0;j<4;j++)
        acc[i][j] = __builtin_amdgcn_mfma_f32_16x16x32_bf16(af[i], bfr[j], acc[i][j], 0,0,0);
  }
  const float alpha = (mode==3) ? bf2f(q1[0]) : 0.f;
#pragma unroll
  for(int j=0;j<4;j++){
    int col = n0 + wc + j*16 + fm;
    if (col >= N) continue;
    float bias = (mode==1) ? bf2f(q1[col]) : 0.f;
#pragma unroll
    for(int i=0;i<4;i++){
      int row = m0 + wr + i*16 + (kg<<2);
#pragma unroll
      for(int rr=0;rr<4;rr++){
        long idx = (long)(row+rr)*ldc + col;
        float v = acc[i][j][rr];
        if (mode==4)      ((float*)Cout)[idx] = v;
        else if (mode==3) ((u16*)Cout)[idx] = f2bf(alpha*v + bf2f(q2[idx]));
        else if (mode==1) ((u16*)Cout)[idx] = f2bf(v + bias);
        else              ((u16*)Cout)[idx] = f2bf(v);
      }
    }
  }
}

// implicit-GEMM 3x3 conv (padded NHWC in, tap-major weights, OC=512)
// phase 0: Out = raw partial (bf16);  1: Out = relu(s*(Out + acc) + b);  2: Out = relu(s*acc + b)
__global__ __launch_bounds__(256,2) void conv3_gemm(
    const u16* __restrict__ Xp, const u16* __restrict__ Wt, int ICt,
    u16* __restrict__ Out, const u16* __restrict__ scale, const u16* __restrict__ bias, int phase)
{
  __shared__ __align__(16) u16 As[128*40];
  __shared__ __align__(16) u16 Bs[128*40];
  const int t = threadIdx.x;
  const int m0 = blockIdx.y<<7, n0 = blockIdx.x<<7;
  const int r = t>>2, q = t&3;
  const int p0 = m0 + r, p1 = p0 + 64;
  const size_t xb0 = ((size_t)((p0>>12)*66 + ((p0>>6)&63))*66 + (p0&63))*ICt + q*8;
  const size_t xb1 = ((size_t)((p1>>12)*66 + ((p1>>6)&63))*66 + (p1&63))*ICt + q*8;
  const u16* W0 = Wt + (size_t)(n0+r)*ICt + q*8;
  const u16* W1 = W0 + (size_t)64*ICt;
  const size_t wtap = (size_t)512*ICt;
  const int wave=t>>6, lane=t&63;
  const int wr=(wave>>1)<<6, wc=(wave&1)<<6, fm=lane&15, kg=lane>>4;
  f32x4 acc[4][4] = {};
  for (int tap=0; tap<9; tap++){
    const size_t toff = (size_t)((tap/3)*66 + (tap%3))*ICt;
    const u16* xa0 = Xp + xb0 + toff;
    const u16* xa1 = Xp + xb1 + toff;
    const u16* wa0 = W0 + (size_t)tap*wtap;
    const u16* wa1 = W1 + (size_t)tap*wtap;
    for (int k0=0; k0<ICt; k0+=32){
      uint4 a0 = *(const uint4*)(xa0+k0);
      uint4 a1 = *(const uint4*)(xa1+k0);
      uint4 b0 = *(const uint4*)(wa0+k0);
      uint4 b1 = *(const uint4*)(wa1+k0);
      __syncthreads();
      *(uint4*)&As[r*40+q*8] = a0;
      *(uint4*)&As[(r+64)*40+q*8] = a1;
      *(uint4*)&Bs[r*40+q*8] = b0;
      *(uint4*)&Bs[(r+64)*40+q*8] = b1;
      __syncthreads();
      bf16x8 af[4], bfr[4];
#pragma unroll
      for(int i=0;i<4;i++) af[i]  = *(const bf16x8*)&As[(wr+i*16+fm)*40 + kg*8];
#pragma unroll
      for(int j=0;j<4;j++) bfr[j] = *(const bf16x8*)&Bs[(wc+j*16+fm)*40 + kg*8];
#pragma unroll
      for(int i=0;i<4;i++)
#pragma unroll
        for(int j=0;j<4;j++)
          acc[i][j] = __builtin_amdgcn_mfma_f32_16x16x32_bf16(af[i], bfr[j], acc[i][j], 0,0,0);
    }
  }
#pragma unroll
  for(int j=0;j<4;j++){
    int col = n0 + wc + j*16 + fm;
    float s = bf2f(scale[col]), bb = bf2f(bias[col]);
#pragma unroll
    for(int i=0;i<4;i++){
      int row = m0 + wr + i*16 + (kg<<2);
#pragma unroll
      for(int rr=0;rr<4;rr++){
        size_t idx = (size_t)(row+rr)*512 + col;
        float v = acc[i][j][rr];
        if (phase == 0)      Out[idx] = f2bf(v);
        else if (phase == 1) Out[idx] = f2bf(fmaxf(s*(bf2f(Out[idx]) + v) + bb, 0.f));
        else                 Out[idx] = f2bf(fmaxf(s*v + bb, 0.f));
      }
    }
  }
}

// PAM row softmax, in-place over rows of 4096 bf16
__global__ __launch_bounds__(256) void k_softmax_pam(u16* __restrict__ attn){
  __shared__ float red[8];
  u16* row = attn + (size_t)blockIdx.x*4096;
  uint4* rv = (uint4*)row;
  const int t = threadIdx.x;
  uint4 c0 = rv[2*t], c1 = rv[2*t+1];
  u16* e0 = (u16*)&c0; u16* e1=(u16*)&c1;
  float v[16];
#pragma unroll
  for(int i=0;i<8;i++){ v[i]=bf2f(e0[i]); v[8+i]=bf2f(e1[i]); }
  float mx = v[0];
#pragma unroll
  for(int i=1;i<16;i++) mx = fmaxf(mx, v[i]);
  mx = wave_max(mx);
  if((t&63)==0) red[t>>6] = mx;
  __syncthreads();
  mx = fmaxf(fmaxf(red[0],red[1]),fmaxf(red[2],red[3]));
  float s = 0.f;
#pragma unroll
  for(int i=0;i<16;i++){ v[i]=__expf(v[i]-mx); s += v[i]; }
  s = wave_sum(s);
  if((t&63)==0) red[4+(t>>6)] = s;
  __syncthreads();
  s = red[4]+red[5]+red[6]+red[7];
  float inv = 1.f/s;
#pragma unroll
  for(int i=0;i<8;i++){ e0[i]=f2bf(v[i]*inv); e1[i]=f2bf(v[8+i]*inv); }
  rv[2*t]=c0; rv[2*t+1]=c1;
}

// CAM softmax: out[c][d] = softmax_d(max_d(att)-att) == softmax_d(-att)
__global__ __launch_bounds__(256) void k_softmax_cam(const float* __restrict__ att, u16* __restrict__ outp){
  __shared__ float red[8];
  const float* row = att + (size_t)blockIdx.x*512;
  const int t = threadIdx.x;
  float a = -row[t], b2 = -row[t+256];
  float mx = wave_max(fmaxf(a,b2));
  if((t&63)==0) red[t>>6]=mx;
  __syncthreads();
  mx = fmaxf(fmaxf(red[0],red[1]),fmaxf(red[2],red[3]));
  float ea = __expf(a-mx), eb = __expf(b2-mx);
  float s = wave_sum(ea+eb);
  if((t&63)==0) red[4+(t>>6)]=s;
  __syncthreads();
  s = red[4]+red[5]+red[6]+red[7];
  float inv = 1.f/s;
  u16* orow = outp + (size_t)blockIdx.x*512;
  orow[t] = f2bf(ea*inv); orow[t+256] = f2bf(eb*inv);
}

// bilinear 2x upsample (half-pixel, clamp), NHWC[16384][81] -> NCHW out (f32 or bf16 per flag)
__global__ __launch_bounds__(128) void k_upsample(const u16* __restrict__ hp, const u16* __restrict__ hc,
                                                  const u16* __restrict__ hf, void* __restrict__ outp,
                                                  const int* __restrict__ flag){
  int bx = blockIdx.x;
  const int y = bx & 127; bx >>= 7;
  const int ch = bx % 81; bx /= 81;
  const int b = bx & 3; const int head = bx >> 2;
  const u16* src = (head==0) ? hp : (head==1 ? hc : hf);
  const int xo = threadIdx.x;
  float fy = y*0.5f - 0.25f, fx = xo*0.5f - 0.25f;
  float fy0 = floorf(fy), fx0 = floorf(fx);
  float wy = fy - fy0, wx = fx - fx0;
  int y0 = max((int)fy0, 0), y1 = min((int)fy0 + 1, 63);
  int x0 = max((int)fx0, 0), x1 = min((int)fx0 + 1, 63);
  const size_t bb = (size_t)b*4096;
  float v00 = bf2f(src[(bb + y0*64 + x0)*81 + ch]);
  float v01 = bf2f(src[(bb + y0*64 + x1)*81 + ch]);
  float v10 = bf2f(src[(bb + y1*64 + x0)*81 + ch]);
  float v11 = bf2f(src[(bb + y1*64 + x1)*81 + ch]);
  float v = (1.f-wy)*((1.f-wx)*v00 + wx*v01) + wy*((1.f-wx)*v10 + wx*v11);
  size_t oidx = ((size_t)(head*324 + b*81 + ch))*16384 + (size_t)y*128 + xo;
  if (*flag) ((float*)outp)[oidx] = v;
  else       ((u16*)outp)[oidx]  = f2bf(v);
}

extern "C" void kernel_launch(void* const* d_in, const int* in_sizes, int n_in,
                              void* d_out, int out_size, void* d_ws, size_t ws_size,
                              hipStream_t stream)
{
  (void)in_sizes; (void)n_in; (void)out_size;
  const void* x   = d_in[0];
  const void* wp1 = d_in[1];
  const void* wc1 = d_in[4];
  const void* wp2 = d_in[15];
  const void* wc2 = d_in[18];
  char* ws = (char*)d_ws;
  const size_t MB = 1048576;
  auto P = [&](size_t off){ return (u16*)(ws + off); };

  // ws probe: plan needs 58 MiB (56 pipeline + 2 params/flag). If less, report via sentinel.
  if (ws_size < 58*MB){
    k_sentinel<<<1,1,0,stream>>>((u16*)d_out, 16.0f * (float)(ws_size / MB));
    return;
  }

  // Pipeline regions (MiB offsets; peak 56). Params region 56-58 never aliased.
  const size_t FP1=0, FC1=16*MB, WTC=32*MB, XP1=41*MB,
               FB=32*MB, FCc=34*MB, FDb=36*MB, FDTb=40*MB, ATTN=44*MB,
               FATb=32*MB, ATTC=36*MB, ATTCS=37*MB, FEATC=40*MB,
               WT2P=16*MB, WT2C=21*MB, XP2=26*MB,
               FUS=16*MB, HP=32*MB, HC=35*MB, HF=40*MB;
  u16* prm = P(56*MB);
  int* FLAG = (int*)(ws + 57*MB + 524288);
  const int SP1=0, BP1=512, SC1=1024, BC1=1536, SP2=2048, BP2=2560, SC2=3072, BC2=3584,
            PBB=4096, PBC=4160, PBD=4224, BP3=4736, BC3=4817, BLOG=4898, ALPHA=4979, BETA=4980,
            PWB=4992, PWC=37760, PWD=70528, W3P=332672, W3C=374144, W3L=415616;

  // ---- dtype probe + param normalization to bf16 ----
  k_probe<<<1, 256, 0, stream>>>((const unsigned*)x, FLAG);
  auto cv = [&](int di, int po, int n){
    k_cvt<<<(n+255)/256, 256, 0, stream>>>(d_in[di], prm+po, n, FLAG);
  };
  cv(2,SP1,512);  cv(3,BP1,512);  cv(5,SC1,512);  cv(6,BC1,512);
  cv(16,SP2,512); cv(17,BP2,512); cv(19,SC2,512); cv(20,BC2,512);
  cv(8,PBB,64);   cv(10,PBC,64);  cv(12,PBD,512);
  cv(24,BP3,81);  cv(26,BC3,81);  cv(22,BLOG,81);
  cv(13,ALPHA,1); cv(14,BETA,1);
  cv(7,PWB,32768); cv(9,PWC,32768); cv(11,PWD,262144);
  cv(23,W3P,41472); cv(25,W3C,41472); cv(21,W3L,41472);

  // ---- conv1 (2048->512), ic-chunked (2 x 1024), per-batch dispatches ----
  k_zero<<<2178, 256, 0, stream>>>((uint4*)P(XP1), 557568);  // 66*66*1024 bf16
  for (int br=0; br<2; br++){
    const void* w1 = br ? wc1 : wp1;
    const u16* s1 = br ? prm+SC1 : prm+SP1;
    const u16* b1 = br ? prm+BC1 : prm+BP1;
    u16* outb = br ? P(FC1) : P(FP1);
    for (int ch=0; ch<2; ch++){
      k_wtrans<<<18432, 256, 0, stream>>>(w1, P(WTC), 2048, 1024, ch*1024, FLAG);
      for (int b=0; b<4; b++){
        // batch offset folded into the flattened (b*2048 + ic) channel axis of NCHW x
        k_pad1<<<dim3(64,16), 256, 0, stream>>>(x, P(XP1), 1024, b*2048 + ch*1024, FLAG);
        conv3_gemm<<<dim3(4,32), 256, 0, stream>>>(P(XP1), P(WTC), 1024, outb + (size_t)b*4096*512, s1, b1, ch);
      }
    }
  }
  // ---- PAM (writes feat_p in-place over FP1) ----
  gemm_nt<<<dim3(1,128), 256, 0, stream>>>(P(FP1), prm+PWB, 64, 512, 512, 512, P(FB), 64, 1, prm+PBB, nullptr);
  gemm_nt<<<dim3(1,128), 256, 0, stream>>>(P(FP1), prm+PWC, 64, 512, 512, 512, P(FCc), 64, 1, prm+PBC, nullptr);
  for (int b=0;b<4;b++){
    const size_t fo = (size_t)b*4096*64, so = (size_t)b*4096*512;
    gemm_nt<<<dim3(4,32), 256, 0, stream>>>(P(FP1)+so, prm+PWD, 512, 512, 512, 512, P(FDb), 512, 1, prm+PBD, nullptr);
    k_transpose<<<dim3(8,64), 256, 0, stream>>>(P(FDb), P(FDTb), 4096, 512);
    for (int c=0;c<4;c++){
      const size_t ro = (size_t)c*1024;
      gemm_nt<<<dim3(32,8), 256, 0, stream>>>(P(FB)+fo+ro*64, P(FCc)+fo, 4096, 64, 64, 64, P(ATTN), 4096, 0, nullptr, nullptr);
      k_softmax_pam<<<1024, 256, 0, stream>>>(P(ATTN));
      gemm_nt<<<dim3(4,8), 256, 0, stream>>>(P(ATTN), P(FDTb), 512, 4096, 4096, 4096, P(FP1)+so+ro*512, 512, 3, prm+ALPHA, P(FP1)+so+ro*512);
    }
  }
  // ---- CAM (per-batch; FEATC separate buffer) ----
  for (int b=0;b<4;b++){
    const size_t so = (size_t)b*4096*512;
    k_transpose<<<dim3(8,64), 256, 0, stream>>>(P(FC1)+so, P(FATb), 4096, 512);
    gemm_nt<<<dim3(4,4), 256, 0, stream>>>(P(FATb), P(FATb), 512, 4096, 4096, 4096, (void*)P(ATTC), 512, 4, nullptr, nullptr);
    k_softmax_cam<<<512, 256, 0, stream>>>((const float*)P(ATTC), P(ATTCS));
    gemm_nt<<<dim3(4,32), 256, 0, stream>>>(P(FC1)+so, P(ATTCS), 512, 512, 512, 512, P(FEATC)+so, 512, 3, prm+BETA, P(FC1)+so);
  }
  // ---- conv2 pair (strip-wise, in-place over FP1 / FEATC) ----
  k_wtrans<<<9216, 256, 0, stream>>>(wp2, P(WT2P), 512, 512, 0, FLAG);
  k_wtrans<<<9216, 256, 0, stream>>>(wc2, P(WT2C), 512, 512, 0, FLAG);
  k_zero<<<2178, 256, 0, stream>>>((uint4*)P(XP2), 557568);  // 2*66*66*512 bf16
  for (int h=0; h<2; h++){
    k_pad_strip<<<2048, 256, 0, stream>>>(P(FP1) + (size_t)h*8192*512, P(XP2), 512, 8192);
    conv3_gemm<<<dim3(4,64), 256, 0, stream>>>(P(XP2), P(WT2P), 512, P(FP1) + (size_t)h*8192*512, prm+SP2, prm+BP2, 2);
  }
  for (int h=0; h<2; h++){
    k_pad_strip<<<2048, 256, 0, stream>>>(P(FEATC) + (size_t)h*8192*512, P(XP2), 512, 8192);
    conv3_gemm<<<dim3(4,64), 256, 0, stream>>>(P(XP2), P(WT2C), 512, P(FEATC) + (size_t)h*8192*512, prm+SC2, prm+BC2, 2);
  }
  // ---- heads + upsample (FP2 lives in FP1 region, FC2 in FEATC region) ----
  k_add_bf16<<<4096, 256, 0, stream>>>(P(FP1), P(FEATC), P(FUS), (long)16384*512);
  gemm_nt<<<dim3(1,128), 256, 0, stream>>>(P(FP1), prm+W3P, 81, 512, 512, 512, P(HP), 81, 1, prm+BP3, nullptr);
  gemm_nt<<<dim3(1,128), 256, 0, stream>>>(P(FEATC), prm+W3C, 81, 512, 512, 512, P(HC), 81, 1, prm+BC3, nullptr);
  gemm_nt<<<dim3(1,128), 256, 0, stream>>>(P(FUS), prm+W3L, 81, 512, 512, 512, P(HF), 81, 1, prm+BLOG, nullptr);
  k_upsample<<<124416, 128, 0, stream>>>(P(HP), P(HC), P(HF), d_out, FLAG);
}